// Round 8
// baseline (162.341 us; speedup 1.0000x reference)
//
#include <hip/hip_runtime.h>
#include <cstdint>
#include <cmath>

#define NROWS 8192
#define KDIM  512            // elements; also bytes/row in fp8

typedef int    i32x4  __attribute__((ext_vector_type(4)));
typedef int    i32x8  __attribute__((ext_vector_type(8)));
typedef float  f32x16 __attribute__((ext_vector_type(16)));
typedef unsigned char u8;

#define AS1(p) ((const __attribute__((address_space(1))) void*)(p))
#define AS3(p) ((__attribute__((address_space(3))) void*)(p))

// contributing blocks at 128x128 tiles: pos upper-tri (64x64 grid) 2080 + neg 4096
#define TOTAL_BLOCKS 6176u

// --- Kernel 1: row L2-normalize fp32 -> fp8 e4m3 (OCP, HW cvt), one wave/row.
// zi rows [0,8192), zj rows [8192,16384). Zeroes the 128 acc slots + ticket.
__global__ __launch_bounds__(256) void nrm_kernel(const float* __restrict__ zi,
                                                  const float* __restrict__ zj,
                                                  u8* __restrict__ out,
                                                  double* __restrict__ acc,
                                                  unsigned* __restrict__ cnt) {
    if (blockIdx.x == 0) {
        if (threadIdx.x < 128) acc[threadIdx.x] = 0.0;
        if (threadIdx.x == 128) *cnt = 0u;
    }
    const int wave = threadIdx.x >> 6;
    const int lane = threadIdx.x & 63;
    const int row  = blockIdx.x * 4 + wave;            // 0..16383
    const float* src = (row < NROWS) ? zi + (size_t)row * KDIM
                                     : zj + (size_t)(row - NROWS) * KDIM;
    float4 a = ((const float4*)src)[lane];
    float4 b = ((const float4*)src)[lane + 64];
    float ss = a.x*a.x + a.y*a.y + a.z*a.z + a.w*a.w
             + b.x*b.x + b.y*b.y + b.z*b.z + b.w*b.w;
    #pragma unroll
    for (int off = 32; off >= 1; off >>= 1) ss += __shfl_xor(ss, off, 64);
    const float inv = 1.0f / fmaxf(sqrtf(ss), 1e-12f);
    int p0 = 0, p1 = 0;
    p0 = __builtin_amdgcn_cvt_pk_fp8_f32(a.x * inv, a.y * inv, p0, false);
    p0 = __builtin_amdgcn_cvt_pk_fp8_f32(a.z * inv, a.w * inv, p0, true);
    p1 = __builtin_amdgcn_cvt_pk_fp8_f32(b.x * inv, b.y * inv, p1, false);
    p1 = __builtin_amdgcn_cvt_pk_fp8_f32(b.z * inv, b.w * inv, p1, true);
    int* dst = (int*)(out + (size_t)row * KDIM);
    dst[lane]      = p0;
    dst[lane + 64] = p1;
}

// --- Kernel 2: fused MX-fp8 A*B^T -> exp(10*dot) -> global sum -> (last) loss.
// R19: TLP, not scheduling. Evidence R11-R18: MFMA-busy is a constant ~21 us
// (= ideal) while the wall ~82 us equals the SERIAL sum of stage+read+MFMA per
// step — and occupancy correlates: 1 blk/CU -> 102-106 us, 2 blk/CU -> 82.
// The 128-AGPR accumulator (+~100 VGPR = 228 regs) capped us at 2 waves/SIMD;
// schedule variants can't overlap what has no co-resident waves to overlap
// with (m114: wave-level TLP is what hides the barrier-drain). Change: tile
// 128x128 / wave 64x64 -> accf[2][2] = 64 AGPR, ~150 regs, launch_bounds
// (256,3) -> 3 blocks/CU, 12 waves/CU, three independent barrier-groups
// anti-phasing per CU. Trade: L2 traffic 596->790 MB (~23 us at L2 BW, not
// binding). Inner mechanics byte-identical: region = 32 rows x 64 B, chunk
// (r,b) at p = r*4 + (b ^ ((r>>1)&3)), staging inverse b=(lane&3)^((lane>>3)&3)
// (verified R2-R18, absmax 0); BK=128 2-half single-buffer 2-barrier loop
// (best measured); XCD band remap (R18, mildly +).
// Fused finalize, FENCE-FREE ticket (R12/R13 post-mortem: the ticket logic was
// correct twice; the threadfence+ACQ_REL acquire = per-block L2 invalidate was
// the 2x poison): relaxed acc atomicAdd -> s_waitcnt vmcnt(0) (ack ordering)
// -> relaxed agent-scope ticket; last block reads slots via atomicAdd(+0.0)
// RMWs at the coherent point — no buffer_inv, no wbl2. Saves the ~6 us third
// launch (R12/R13 fixed-cost delta). Discriminator: WRITE_SIZE must stay
// ~97 KB; if it doubles, the ticket is poisoning L2 again -> unfuse.
__global__ __launch_bounds__(256, 3) void gemm_exp_reduce(const u8* __restrict__ A,
                                                          const u8* __restrict__ B,
                                                          double* __restrict__ acc,
                                                          unsigned* __restrict__ cnt,
                                                          float* __restrict__ out) {
    // XCD-band remap (bijective on 8192): xcd = bid&7 owns bx === xcd (mod 8).
    const int bid = blockIdx.x + 128 * blockIdx.y;
    const int bx  = (bid & 7) + 8 * ((bid >> 3) & 15);   // 0..127
    const int by  = bid >> 7;                            // 0..63
    const bool pos = (bx < 64);
    if (pos && bx < by) return;      // strict lower-tri pos block: mirror elsewhere

    __shared__ u8 lA[2][128 * 64];   // 2 k-halves x 8 KB (4 regions of 32r x 64B)
    __shared__ u8 lB[2][128 * 64];   // 2 k-halves x 8 KB (4 regions)
    __shared__ float red[4];
    __shared__ double dred[2];
    __shared__ unsigned amLast;

    const int tid  = threadIdx.x;
    const int lane = tid & 63;
    const int wave = tid >> 6;                 // 0..3, grid 2Mx2N
    const int m0   = by * 128;
    const int n0   = bx * 128;
    const int wm   = (wave >> 1) * 64;
    const int wn   = (wave & 1) * 64;

    f32x16 accf[2][2];
    #pragma unroll
    for (int i = 0; i < 2; ++i)
        #pragma unroll
        for (int j = 0; j < 2; ++j)
            #pragma unroll
            for (int r = 0; r < 16; ++r)
                accf[i][j][r] = 0.f;

    // staging: wave w stages region w (rows 32w..32w+31) of BOTH A and B:
    // 2 chunks of 16 rows x 1024 B per k-half -> 4 loads/thread/half.
    const int bsw = (lane & 3) ^ ((lane >> 3) & 3);
    const u8* gA0 = A + (size_t)(m0 + wave * 32 + (lane >> 2)) * KDIM + bsw * 16;
    const u8* gB0 = B + (size_t)(n0 + wave * 32 + (lane >> 2)) * KDIM + bsw * 16;
    const int ldsO = wave * 2048 + lane * 16;

    // fragment read: lane row r=lane&31, k-half-of-64 q=lane>>5;
    // swizzled slot p = r*4 + ((2q) ^ ((r>>1)&3)); partner chunk at ^16.
    const int r_  = lane & 31;
    const int q_  = lane >> 5;
    const int p16 = (r_ * 4 + ((2 * q_) ^ ((r_ >> 1) & 3))) * 16;
    const int aT0 = (wave >> 1) * 2;   // A regions aT0..aT0+1 (64 rows)
    const int bT0 = (wave & 1) * 2;    // B regions bT0..bT0+1 (64 rows)

    for (int k0 = 0; k0 < KDIM; k0 += 128) {   // BK=128: 4 iters, 8 barriers total
        __syncthreads();   // previous iteration's ds_reads done before overwrite
        #pragma unroll
        for (int h = 0; h < 2; ++h) {
            const size_t kb = (size_t)k0 + h * 64;
            #pragma unroll
            for (int c = 0; c < 2; ++c)
                __builtin_amdgcn_global_load_lds(AS1(gA0 + kb + (size_t)c * 16 * KDIM),
                                                 AS3(&lA[h][ldsO + c * 1024]), 16, 0, 0);
            #pragma unroll
            for (int c = 0; c < 2; ++c)
                __builtin_amdgcn_global_load_lds(AS1(gB0 + kb + (size_t)c * 16 * KDIM),
                                                 AS3(&lB[h][ldsO + c * 1024]), 16, 0, 0);
        }
        __syncthreads();   // vmcnt drain + barrier: both k-halves ready

        #pragma unroll
        for (int h = 0; h < 2; ++h) {   // 8 MFMAs between barrier pairs
            i32x8 af[2], bfr[2];
            #pragma unroll
            for (int mi = 0; mi < 2; ++mi) {
                const int off = (aT0 + mi) * 2048 + p16;
                *(i32x4*)&af[mi]       = *(const i32x4*)&lA[h][off];
                *((i32x4*)&af[mi] + 1) = *(const i32x4*)&lA[h][off ^ 16];
            }
            #pragma unroll
            for (int ni = 0; ni < 2; ++ni) {
                const int off = (bT0 + ni) * 2048 + p16;
                *(i32x4*)&bfr[ni]       = *(const i32x4*)&lB[h][off];
                *((i32x4*)&bfr[ni] + 1) = *(const i32x4*)&lB[h][off ^ 16];
            }
            #pragma unroll
            for (int mi = 0; mi < 2; ++mi)
                #pragma unroll
                for (int ni = 0; ni < 2; ++ni)
                    accf[mi][ni] = __builtin_amdgcn_mfma_scale_f32_32x32x64_f8f6f4(
                        af[mi], bfr[ni], accf[mi][ni],
                        0, 0,                 // cbsz=fp8(e4m3), blgp=fp8(e4m3)
                        0, 0x7f7f7f7f,        // scale_a: every byte = 2^0
                        0, 0x7f7f7f7f);       // scale_b
        }
    }

    // epilogue: exp(10*d) = exp2(d*10/ln2); diagonal pos block skips rr==cc
    const float LOG2E10 = 14.4269504088896341f;
    float part = 0.f;
    if (pos && bx == by) {
        #pragma unroll
        for (int mi = 0; mi < 2; ++mi)
            #pragma unroll
            for (int ni = 0; ni < 2; ++ni)
                #pragma unroll
                for (int r = 0; r < 16; ++r) {
                    // C/D 32x32: col=lane&31, row=(r&3)+8*(r>>2)+4*(lane>>5)
                    int rr = m0 + wm + mi * 32 + ((r & 3) + 8 * (r >> 2) + 4 * q_);
                    int cc = n0 + wn + ni * 32 + r_;
                    if (rr != cc) part += exp2f(accf[mi][ni][r] * LOG2E10);
                }
    } else {
        #pragma unroll
        for (int mi = 0; mi < 2; ++mi)
            #pragma unroll
            for (int ni = 0; ni < 2; ++ni)
                #pragma unroll
                for (int r = 0; r < 16; ++r)
                    part += exp2f(accf[mi][ni][r] * LOG2E10);
    }

    #pragma unroll
    for (int off = 32; off >= 1; off >>= 1) part += __shfl_xor(part, off, 64);
    if (lane == 0) red[wave] = part;
    __syncthreads();
    if (tid == 0) {
        double s = (double)red[0] + (double)red[1] + (double)red[2] + (double)red[3];
        if (pos && bx > by) s *= 2.0;    // stands in for its skipped mirror
        atomicAdd(&acc[(pos ? 0 : 64) + (((unsigned)bx * 7 + (unsigned)by) & 63)], s);
        // ensure the acc add is ack'd at the coherent point BEFORE the ticket;
        // no threadfence (no wbl2), no acquire (no L2 invalidate).
        asm volatile("s_waitcnt vmcnt(0)" ::: "memory");
        unsigned prev = __hip_atomic_fetch_add(cnt, 1u, __ATOMIC_RELAXED,
                                               __HIP_MEMORY_SCOPE_AGENT);
        amLast = (prev == TOTAL_BLOCKS - 1u) ? 1u : 0u;
    }
    __syncthreads();

    // fused finalize: last block reads the 128 slots via atomic RMW (+0.0) —
    // coherent-point reads, no cache maintenance. Slots 0..63 pos, 64..127 neg.
    if (amLast) {
        double v = 0.0;
        if (tid < 128) v = atomicAdd(&acc[tid], 0.0);
        #pragma unroll
        for (int off = 32; off >= 1; off >>= 1) v += __shfl_xor(v, off, 64);
        if (tid == 0)  dred[0] = v;   // pos sum
        if (tid == 64) dred[1] = v;   // neg sum
        __syncthreads();
        if (tid == 0) {
            double p = dred[0] + 8192.0 * exp(10.0);   // exact pos diagonal
            out[0] = (float)log1p(dred[1] / p);
        }
    }
}

extern "C" void kernel_launch(void* const* d_in, const int* in_sizes, int n_in,
                              void* d_out, int out_size, void* d_ws, size_t ws_size,
                              hipStream_t stream) {
    const float* zi = (const float*)d_in[0];
    const float* zj = (const float*)d_in[1];
    u8* nrm = (u8*)d_ws;                                      // [16384][512] fp8 = 8 MB
    double* acc = (double*)((char*)d_ws + (size_t)16384 * 512);
    unsigned* cnt = (unsigned*)(acc + 128);

    nrm_kernel<<<4096, 256, 0, stream>>>(zi, zj, nrm, acc, cnt);
    dim3 grid(128, 64);   // x: 16384/128 n-tiles, y: 8192/128 m-tiles
    gemm_exp_reduce<<<grid, 256, 0, stream>>>(nrm, nrm, acc, cnt, (float*)d_out);
}